// Round 15
// baseline (152.044 us; speedup 1.0000x reference)
//
#include <hip/hip_runtime.h>

typedef unsigned short u16;
typedef unsigned int u32;
typedef unsigned long long u64;
typedef __attribute__((ext_vector_type(8))) short short8;
typedef __attribute__((ext_vector_type(4))) float f32x4;

#define NN 8192
#define FIN 512
#define FO 200
#define FP 208
#define CO 20
#define CAP 256
#define ALPHA 0.2f
#define GEMM_BLOCKS 256
#define COMPACT_BLOCKS 2048

__device__ __forceinline__ u16 f2bf(float f){
  union { float f; unsigned u; } c; c.f = f;
  unsigned u = c.u;
  return (u16)((u + 0x7fffu + ((u >> 16) & 1u)) >> 16);
}
__device__ __forceinline__ float bf2f(u16 s){
  union { unsigned u; float f; } c; c.u = ((unsigned)s) << 16;
  return c.f;
}

// ---- PROBE: pure read of support, identical pattern to compact role --------
__launch_bounds__(256)
__global__ void k_probe(const float* __restrict__ support, float* __restrict__ dummy){
  int tid = threadIdx.x, lane = tid & 63, wid = tid >> 6;
  int i = blockIdx.x * 4 + wid;
  const f32x4* row4 = (const f32x4*)(support + (size_t)i * NN);
  float acc = 0.f;
  f32x4 bufA[8], bufB[8];
#define LOAD_GROUP(buf, g) { \
    _Pragma("unroll") \
    for (int k = 0; k < 8; k++) buf[k] = __builtin_nontemporal_load(&row4[(g) * 512 + k * 64 + lane]); }
#define SUM_GROUP(buf) { \
    _Pragma("unroll") \
    for (int k = 0; k < 8; k++) acc += buf[k][0] + buf[k][1] + buf[k][2] + buf[k][3]; }
  LOAD_GROUP(bufA, 0)
  LOAD_GROUP(bufB, 1)
  SUM_GROUP(bufA)
  LOAD_GROUP(bufA, 2)
  SUM_GROUP(bufB)
  LOAD_GROUP(bufB, 3)
  SUM_GROUP(bufA)
  SUM_GROUP(bufB)
#undef LOAD_GROUP
#undef SUM_GROUP
  dummy[(size_t)blockIdx.x * 256 + tid] = acc;
}

// ---- K0: WbT = bf16(W^T) padded to 208 cols (tiny) -------------------------
__launch_bounds__(256)
__global__ void k_prep(const float* __restrict__ W, u16* __restrict__ WbT){
  int b = blockIdx.x;
  for (int k = threadIdx.x; k < FIN; k += 256) {
    float v = (b < FO) ? W[(size_t)k * FO + b] : 0.f;
    WbT[(size_t)b * FIN + k] = f2bf(v);
  }
}

// ====== K1 fused: [0,256) gemm FIRST (overlaps) | [256,2304) compact ========
__launch_bounds__(256)
__global__ void k_main(const float* __restrict__ support, const float* __restrict__ x,
                       const u16* __restrict__ WbT, const float* __restrict__ a1,
                       const float* __restrict__ a2, u16* __restrict__ hb,
                       float* __restrict__ f1, float* __restrict__ f2,
                       int* __restrict__ nnzg, u16* __restrict__ idxg,
                       float* __restrict__ valg){
  int tid = threadIdx.x, lane = tid & 63, wid = tid >> 6;
  int bid = blockIdx.x;

  if (bid >= GEMM_BLOCKS) {
    int i = (bid - GEMM_BLOCKS) * 4 + wid;
    const f32x4* row4 = (const f32x4*)(support + (size_t)i * NN);
    u16* ig = idxg + (size_t)i * CAP;
    float* vg = valg + (size_t)i * CAP;
    u64 lanemask = (1ull << lane) - 1ull;
    int base = 0;
    f32x4 bufA[8], bufB[8];
#define LOAD_GROUP(buf, g) { \
    _Pragma("unroll") \
    for (int k = 0; k < 8; k++) buf[k] = __builtin_nontemporal_load(&row4[(g) * 512 + k * 64 + lane]); }
#define PROC_GROUP(buf, g) { \
    _Pragma("unroll") \
    for (int k = 0; k < 8; k++) { \
      _Pragma("unroll") \
      for (int c = 0; c < 4; c++) { \
        float val = buf[k][c]; \
        bool p = val > 0.f; \
        u64 mk = __ballot(p); \
        if (p) { \
          int pos = base + __popcll(mk & lanemask); \
          if (pos < CAP) { \
            ig[pos] = (u16)((g) * 2048 + (k * 64 + lane) * 4 + c); \
            vg[pos] = val; \
          } \
        } \
        base += __popcll(mk); \
      } } }
    LOAD_GROUP(bufA, 0)
    LOAD_GROUP(bufB, 1)
    PROC_GROUP(bufA, 0)
    LOAD_GROUP(bufA, 2)
    PROC_GROUP(bufB, 1)
    LOAD_GROUP(bufB, 3)
    PROC_GROUP(bufA, 2)
    PROC_GROUP(bufB, 3)
#undef LOAD_GROUP
#undef PROC_GROUP
    if (lane == 0) nnzg[i] = min(base, CAP);
    return;
  }

  // gemm role: A staged from f32 x directly, B from WbT
  __shared__ __align__(16) u16 As[32 * 32];
  __shared__ __align__(16) u16 Bs[FP * 32];
  __shared__ float a1s[FP], a2s[FP];
  __shared__ float fpart[2][4][32];
  int rb = bid * 32;
  if (tid < FP) {
    a1s[tid] = (tid < FO) ? a1[tid] : 0.f;
    a2s[tid] = (tid < FO) ? a2[tid] : 0.f;
  }
  f32x4 acc[7];
  #pragma unroll
  for (int n = 0; n < 7; n++) acc[n] = (f32x4){0.f, 0.f, 0.f, 0.f};
  for (int k0 = 0; k0 < FIN; k0 += 32) {
    __syncthreads();
    {
      int r = tid >> 3, kk = (tid & 7) * 4;
      const f32x4* xp = (const f32x4*)(x + (size_t)(rb + r) * FIN + k0 + kk);
      f32x4 xv = *xp;
      ushort4 hv;
      hv.x = f2bf(xv[0]); hv.y = f2bf(xv[1]); hv.z = f2bf(xv[2]); hv.w = f2bf(xv[3]);
      *(ushort4*)&As[r * 32 + (((kk >> 3) ^ ((r >> 1) & 3)) * 8) + (kk & 7)] = hv;
    }
    for (int c = tid; c < FP * 4; c += 256) {
      int col = c >> 2, j = c & 3;
      uint4 bv = *(const uint4*)(WbT + (size_t)col * FIN + k0 + j * 8);
      *(uint4*)&Bs[col * 32 + (j ^ ((col >> 1) & 3)) * 8] = bv;
    }
    __syncthreads();
    int jr = lane >> 4;
    #pragma unroll
    for (int n = 0; n < 7; n++) {
      int t = wid + 4 * n;
      if (t < 26) {
        int rt = t / 13, ct = t % 13;
        int lr = rt * 16 + (lane & 15);
        short8 af = *(const short8*)&As[lr * 32 + (jr ^ ((lr >> 1) & 3)) * 8];
        int col = ct * 16 + (lane & 15);
        short8 bfv = *(const short8*)&Bs[col * 32 + (jr ^ ((col >> 1) & 3)) * 8];
        acc[n] = __builtin_amdgcn_mfma_f32_16x16x32_bf16(af, bfv, acc[n], 0, 0, 0);
      }
    }
  }
  float f1a[2][4] = {{0.f,0.f,0.f,0.f},{0.f,0.f,0.f,0.f}};
  float f2a[2][4] = {{0.f,0.f,0.f,0.f},{0.f,0.f,0.f,0.f}};
  #pragma unroll
  for (int n = 0; n < 7; n++) {
    int t = wid + 4 * n;
    if (t < 26) {
      int rt = t / 13, ct = t % 13;
      int col = ct * 16 + (lane & 15);
      float av1 = a1s[col], av2 = a2s[col];
      int rbase = rb + rt * 16 + 4 * (lane >> 4);
      #pragma unroll
      for (int q = 0; q < 4; q++) {
        float hv = acc[n][q];
        if (col < FO) hb[(size_t)(rbase + q) * FO + col] = f2bf(hv);
        f1a[rt][q] = fmaf(hv, av1, f1a[rt][q]);
        f2a[rt][q] = fmaf(hv, av2, f2a[rt][q]);
      }
    }
  }
  #pragma unroll
  for (int rt = 0; rt < 2; rt++) {
    #pragma unroll
    for (int q = 0; q < 4; q++) {
      float v1 = f1a[rt][q], v2 = f2a[rt][q];
      #pragma unroll
      for (int o = 1; o < 16; o <<= 1) { v1 += __shfl_xor(v1, o); v2 += __shfl_xor(v2, o); }
      if ((lane & 15) == 0) {
        int row = rt * 16 + 4 * (lane >> 4) + q;
        fpart[0][wid][row] = v1;
        fpart[1][wid][row] = v2;
      }
    }
  }
  __syncthreads();
  if (tid < 32) {
    f1[rb + tid] = fpart[0][0][tid] + fpart[0][1][tid] + fpart[0][2][tid] + fpart[0][3][tid];
    f2[rb + tid] = fpart[1][0][tid] + fpart[1][1][tid] + fpart[1][2][tid] + fpart[1][3][tid];
  }
}

// ------- K2: softmax + h'=elu(att@h) + g = h'@W0  (2 rows/block) ------------
__launch_bounds__(256)
__global__ void k_gather(const int* __restrict__ nnzg, const u16* __restrict__ idxg,
                         const float* __restrict__ f1, const float* __restrict__ f2,
                         const u16* __restrict__ hb, const float* __restrict__ W0,
                         float* __restrict__ g){
  int tid = threadIdx.x;
  int half = tid >> 7, t = tid & 127;
  int lane = tid & 63, hw = (tid >> 6) & 1;
  int i = blockIdx.x * 2 + half;
  __shared__ int s_j[2][CAP];
  __shared__ float s_w[2][CAP];
  __shared__ float s_red[2][4];
  __shared__ float s_hp[2][FO];
  __shared__ float s_part[2][120];
  int nnz = nnzg[i];
  for (int u = t; u < nnz; u += 128) s_j[half][u] = idxg[(size_t)i * CAP + u];
  __syncthreads();
  float fi = f1[i];
  float e0 = -1e30f, e1 = -1e30f;
  if (t < nnz)       { float e = fi + f2[s_j[half][t]];       e0 = e > 0.f ? e : ALPHA * e; }
  if (t + 128 < nnz) { float e = fi + f2[s_j[half][t + 128]]; e1 = e > 0.f ? e : ALPHA * e; }
  float m = fmaxf(e0, e1);
  #pragma unroll
  for (int o = 32; o; o >>= 1) m = fmaxf(m, __shfl_xor(m, o));
  if (lane == 0) s_red[half][hw] = m;
  __syncthreads();
  m = fmaxf(s_red[half][0], s_red[half][1]);
  float p0 = (t < nnz)       ? __expf(e0 - m) : 0.f;
  float p1 = (t + 128 < nnz) ? __expf(e1 - m) : 0.f;
  float s = p0 + p1;
  #pragma unroll
  for (int o = 32; o; o >>= 1) s += __shfl_xor(s, o);
  if (lane == 0) s_red[half][2 + hw] = s;
  __syncthreads();
  float rs = 1.0f / (s_red[half][2] + s_red[half][3]);
  if (t < nnz)       s_w[half][t]       = p0 * rs;
  if (t + 128 < nnz) s_w[half][t + 128] = p1 * rs;
  __syncthreads();
  if (t < 100) {
    float ax = 0.f, ay = 0.f;
    int jj = 0;
    for (; jj + 8 <= nnz; jj += 8) {
      #pragma unroll
      for (int q = 0; q < 8; q++) {
        int j = s_j[half][jj + q];
        float w = s_w[half][jj + q];
        u32 hv = *(const u32*)&hb[(size_t)j * FO + 2 * t];
        ax = fmaf(w, bf2f((u16)(hv & 0xffffu)), ax);
        ay = fmaf(w, bf2f((u16)(hv >> 16)), ay);
      }
    }
    for (; jj < nnz; jj++) {
      int j = s_j[half][jj];
      float w = s_w[half][jj];
      u32 hv = *(const u32*)&hb[(size_t)j * FO + 2 * t];
      ax = fmaf(w, bf2f((u16)(hv & 0xffffu)), ax);
      ay = fmaf(w, bf2f((u16)(hv >> 16)), ay);
    }
    s_hp[half][2 * t]     = ax > 0.f ? ax : expm1f(ax);
    s_hp[half][2 * t + 1] = ay > 0.f ? ay : expm1f(ay);
  }
  __syncthreads();
  if (t < 120) {
    int c = t % 20, dg = t / 20;
    float acc = 0.f;
    for (int d = dg; d < FO; d += 6)
      acc = fmaf(s_hp[half][d], W0[d * CO + c], acc);
    s_part[half][t] = acc;
  }
  __syncthreads();
  if (t < 20) {
    float a = s_part[half][t] + s_part[half][t + 20] + s_part[half][t + 40]
            + s_part[half][t + 60] + s_part[half][t + 80] + s_part[half][t + 100];
    g[(size_t)i * CO + t] = a;
  }
}

// ---------------- K3: out = support @ g  (sparse rep, LDS-staged) ------------
__launch_bounds__(256)
__global__ void k_out(const int* __restrict__ nnzg, const u16* __restrict__ idxg,
                      const float* __restrict__ valg, const float* __restrict__ g,
                      float* __restrict__ out){
  int tid = threadIdx.x, lane = tid & 63, wid = tid >> 6;
  int i = blockIdx.x * 4 + wid;
  __shared__ int s_j[4][CAP];
  __shared__ float s_w[4][CAP];
  int nnz = nnzg[i];
  for (int t = lane; t < nnz; t += 64) {
    s_j[wid][t] = idxg[(size_t)i * CAP + t];
    s_w[wid][t] = valg[(size_t)i * CAP + t];
  }
  __syncthreads();
  int c = lane % 20, grp = lane / 20;
  float acc = 0.f;
  if (grp < 3) {
    for (int jj = grp; jj < nnz; jj += 3)
      acc = fmaf(s_w[wid][jj], g[(size_t)s_j[wid][jj] * CO + c], acc);
  }
  float b1 = __shfl(acc, lane + 20);
  float b2 = __shfl(acc, lane + 40);
  if (lane < 20) out[(size_t)i * CO + lane] = acc + b1 + b2;
}

extern "C" void kernel_launch(void* const* d_in, const int* in_sizes, int n_in,
                              void* d_out, int out_size, void* d_ws, size_t ws_size,
                              hipStream_t stream) {
  (void)in_sizes; (void)n_in; (void)out_size; (void)ws_size;
  const float* x       = (const float*)d_in[0];
  const float* support = (const float*)d_in[1];
  const float* W       = (const float*)d_in[2];
  const float* a1      = (const float*)d_in[3];
  const float* a2      = (const float*)d_in[4];
  const float* W0      = (const float*)d_in[5];
  char* ws = (char*)d_ws;
  u16*   WbT  = (u16*)  (ws + 0);          // 208*512*2   = 212992
  float* f1   = (float*)(ws + 212992);     // 8192*4      = 32768
  float* f2   = (float*)(ws + 245760);     // 8192*4      = 32768
  u16*   hb   = (u16*)  (ws + 278528);     // 8192*200*2  = 3276800
  float* g    = (float*)(ws + 3555328);    // 8192*20*4   = 655360
  int*   nnzg = (int*)  (ws + 4210688);    // 8192*4      = 32768
  u16*   idxg = (u16*)  (ws + 4243456);    // 8192*256*2  = 4194304
  float* valg = (float*)(ws + 8437760);    // 8192*256*4  = 8388608
  float* dmy  = (float*)(ws + 16826368);   // 2048*256*4  = 2097152
  float* outp = (float*)d_out;

  k_probe <<<COMPACT_BLOCKS, 256, 0, stream>>>(support, dmy);   // PROBE (remove next round)
  k_prep  <<<FP, 256, 0, stream>>>(W, WbT);
  k_main  <<<GEMM_BLOCKS + COMPACT_BLOCKS, 256, 0, stream>>>(support, x, WbT, a1, a2,
                                                             hb, f1, f2, nnzg, idxg, valg);
  k_gather<<<NN / 2, 256, 0, stream>>>(nnzg, idxg, f1, f2, hb, W0, g);
  k_out   <<<NN / 4, 256, 0, stream>>>(nnzg, idxg, valg, g, outp);
}

// Round 16
// 117.028 us; speedup vs baseline: 1.2992x; 1.2992x over previous
//
#include <hip/hip_runtime.h>

typedef unsigned short u16;
typedef unsigned int u32;
typedef unsigned long long u64;
typedef __attribute__((ext_vector_type(8))) short short8;
typedef __attribute__((ext_vector_type(4))) float f32x4;

#define NN 8192
#define FIN 512
#define FO 200
#define FP 208
#define CO 20
#define CAP 256
#define ALPHA 0.2f
#define GEMM_BLOCKS 256
#define COMPACT_BLOCKS 2048

__device__ __forceinline__ u16 f2bf(float f){
  union { float f; unsigned u; } c; c.f = f;
  unsigned u = c.u;
  return (u16)((u + 0x7fffu + ((u >> 16) & 1u)) >> 16);
}
__device__ __forceinline__ float bf2f(u16 s){
  union { unsigned u; float f; } c; c.u = ((unsigned)s) << 16;
  return c.f;
}

// ---- K0: WbT = bf16(W^T) padded to 208 cols (tiny) -------------------------
__launch_bounds__(256)
__global__ void k_prep(const float* __restrict__ W, u16* __restrict__ WbT){
  int b = blockIdx.x;
  for (int k = threadIdx.x; k < FIN; k += 256) {
    float v = (b < FO) ? W[(size_t)k * FO + b] : 0.f;
    WbT[(size_t)b * FIN + k] = f2bf(v);
  }
}

// ====== K1 fused: [0,256) gemm FIRST (overlaps) | [256,2304) compact ========
__launch_bounds__(256)
__global__ void k_main(const float* __restrict__ support, const float* __restrict__ x,
                       const u16* __restrict__ WbT, const float* __restrict__ a1,
                       const float* __restrict__ a2, u16* __restrict__ hb,
                       float* __restrict__ f1, float* __restrict__ f2,
                       int* __restrict__ nnzg, u16* __restrict__ idxg,
                       float* __restrict__ valg){
  int tid = threadIdx.x, lane = tid & 63, wid = tid >> 6;
  int bid = blockIdx.x;

  if (bid >= GEMM_BLOCKS) {
    // ==== compact role: per-lane register bitmap + scan + L2 re-gather ====
    int i = (bid - GEMM_BLOCKS) * 4 + wid;
    const float* srow = support + (size_t)i * NN;
    const f32x4* row4 = (const f32x4*)srow;
    u16* ig = idxg + (size_t)i * CAP;
    float* vg = valg + (size_t)i * CAP;
    f32x4 bufA[8], bufB[8];
    u64 w0 = 0, w1 = 0;
#define LOAD_GROUP(buf, g) { \
    _Pragma("unroll") \
    for (int k = 0; k < 8; k++) buf[k] = row4[(g) * 512 + k * 64 + lane]; }
#define BITS_GROUP(buf, g) { \
    _Pragma("unroll") \
    for (int k = 0; k < 8; k++) { \
      u32 nib = (u32)(buf[k][0] > 0.f) | ((u32)(buf[k][1] > 0.f) << 1) \
              | ((u32)(buf[k][2] > 0.f) << 2) | ((u32)(buf[k][3] > 0.f) << 3); \
      int kk = (g) * 8 + k; \
      if (kk < 16) w0 |= ((u64)nib) << (4 * kk); \
      else         w1 |= ((u64)nib) << (4 * (kk - 16)); \
    } }
    LOAD_GROUP(bufA, 0)
    LOAD_GROUP(bufB, 1)
    BITS_GROUP(bufA, 0)
    LOAD_GROUP(bufA, 2)
    BITS_GROUP(bufB, 1)
    LOAD_GROUP(bufB, 3)
    BITS_GROUP(bufA, 2)
    BITS_GROUP(bufB, 3)
#undef LOAD_GROUP
#undef BITS_GROUP
    int cnt = __popcll(w0) + __popcll(w1);
    int sc = cnt;
    #pragma unroll
    for (int o = 1; o < 64; o <<= 1) { int t2 = __shfl_up(sc, o); if (lane >= o) sc += t2; }
    int pos = sc - cnt;
    int total = __shfl(sc, 63);
    // writeout: ~1.3 iterations/lane avg; value re-read from L2-resident row
    while (w0) {
      int b = __ffsll((long long)w0) - 1;
      w0 &= w0 - 1;
      if (pos < CAP) {
        int kk = b >> 2;
        int col = (kk >> 3) * 2048 + (kk & 7) * 256 + lane * 4 + (b & 3);
        ig[pos] = (u16)col;
        vg[pos] = srow[col];
      }
      pos++;
    }
    while (w1) {
      int b = __ffsll((long long)w1) - 1;
      w1 &= w1 - 1;
      if (pos < CAP) {
        int kk = b >> 2;
        int col = 4096 + (kk >> 3) * 2048 + (kk & 7) * 256 + lane * 4 + (b & 3);
        ig[pos] = (u16)col;
        vg[pos] = srow[col];
      }
      pos++;
    }
    if (lane == 0) nnzg[i] = min(total, CAP);
    return;
  }

  // gemm role: A staged from f32 x directly, B from WbT
  __shared__ __align__(16) u16 As[32 * 32];
  __shared__ __align__(16) u16 Bs[FP * 32];
  __shared__ float a1s[FP], a2s[FP];
  __shared__ float fpart[2][4][32];
  int rb = bid * 32;
  if (tid < FP) {
    a1s[tid] = (tid < FO) ? a1[tid] : 0.f;
    a2s[tid] = (tid < FO) ? a2[tid] : 0.f;
  }
  f32x4 acc[7];
  #pragma unroll
  for (int n = 0; n < 7; n++) acc[n] = (f32x4){0.f, 0.f, 0.f, 0.f};
  for (int k0 = 0; k0 < FIN; k0 += 32) {
    __syncthreads();
    {
      int r = tid >> 3, kk = (tid & 7) * 4;
      const f32x4* xp = (const f32x4*)(x + (size_t)(rb + r) * FIN + k0 + kk);
      f32x4 xv = *xp;
      ushort4 hv;
      hv.x = f2bf(xv[0]); hv.y = f2bf(xv[1]); hv.z = f2bf(xv[2]); hv.w = f2bf(xv[3]);
      *(ushort4*)&As[r * 32 + (((kk >> 3) ^ ((r >> 1) & 3)) * 8) + (kk & 7)] = hv;
    }
    for (int c = tid; c < FP * 4; c += 256) {
      int col = c >> 2, j = c & 3;
      uint4 bv = *(const uint4*)(WbT + (size_t)col * FIN + k0 + j * 8);
      *(uint4*)&Bs[col * 32 + (j ^ ((col >> 1) & 3)) * 8] = bv;
    }
    __syncthreads();
    int jr = lane >> 4;
    #pragma unroll
    for (int n = 0; n < 7; n++) {
      int t = wid + 4 * n;
      if (t < 26) {
        int rt = t / 13, ct = t % 13;
        int lr = rt * 16 + (lane & 15);
        short8 af = *(const short8*)&As[lr * 32 + (jr ^ ((lr >> 1) & 3)) * 8];
        int col = ct * 16 + (lane & 15);
        short8 bfv = *(const short8*)&Bs[col * 32 + (jr ^ ((col >> 1) & 3)) * 8];
        acc[n] = __builtin_amdgcn_mfma_f32_16x16x32_bf16(af, bfv, acc[n], 0, 0, 0);
      }
    }
  }
  float f1a[2][4] = {{0.f,0.f,0.f,0.f},{0.f,0.f,0.f,0.f}};
  float f2a[2][4] = {{0.f,0.f,0.f,0.f},{0.f,0.f,0.f,0.f}};
  #pragma unroll
  for (int n = 0; n < 7; n++) {
    int t = wid + 4 * n;
    if (t < 26) {
      int rt = t / 13, ct = t % 13;
      int col = ct * 16 + (lane & 15);
      float av1 = a1s[col], av2 = a2s[col];
      int rbase = rb + rt * 16 + 4 * (lane >> 4);
      #pragma unroll
      for (int q = 0; q < 4; q++) {
        float hv = acc[n][q];
        if (col < FO) hb[(size_t)(rbase + q) * FO + col] = f2bf(hv);
        f1a[rt][q] = fmaf(hv, av1, f1a[rt][q]);
        f2a[rt][q] = fmaf(hv, av2, f2a[rt][q]);
      }
    }
  }
  #pragma unroll
  for (int rt = 0; rt < 2; rt++) {
    #pragma unroll
    for (int q = 0; q < 4; q++) {
      float v1 = f1a[rt][q], v2 = f2a[rt][q];
      #pragma unroll
      for (int o = 1; o < 16; o <<= 1) { v1 += __shfl_xor(v1, o); v2 += __shfl_xor(v2, o); }
      if ((lane & 15) == 0) {
        int row = rt * 16 + 4 * (lane >> 4) + q;
        fpart[0][wid][row] = v1;
        fpart[1][wid][row] = v2;
      }
    }
  }
  __syncthreads();
  if (tid < 32) {
    f1[rb + tid] = fpart[0][0][tid] + fpart[0][1][tid] + fpart[0][2][tid] + fpart[0][3][tid];
    f2[rb + tid] = fpart[1][0][tid] + fpart[1][1][tid] + fpart[1][2][tid] + fpart[1][3][tid];
  }
}

// ------- K2: softmax + h'=elu(att@h) + g = h'@W0  (2 rows/block) ------------
__launch_bounds__(256)
__global__ void k_gather(const int* __restrict__ nnzg, const u16* __restrict__ idxg,
                         const float* __restrict__ f1, const float* __restrict__ f2,
                         const u16* __restrict__ hb, const float* __restrict__ W0,
                         float* __restrict__ g){
  int tid = threadIdx.x;
  int half = tid >> 7, t = tid & 127;
  int lane = tid & 63, hw = (tid >> 6) & 1;
  int i = blockIdx.x * 2 + half;
  __shared__ int s_j[2][CAP];
  __shared__ float s_w[2][CAP];
  __shared__ float s_red[2][4];
  __shared__ float s_hp[2][FO];
  __shared__ float s_part[2][120];
  int nnz = nnzg[i];
  for (int u = t; u < nnz; u += 128) s_j[half][u] = idxg[(size_t)i * CAP + u];
  __syncthreads();
  float fi = f1[i];
  float e0 = -1e30f, e1 = -1e30f;
  if (t < nnz)       { float e = fi + f2[s_j[half][t]];       e0 = e > 0.f ? e : ALPHA * e; }
  if (t + 128 < nnz) { float e = fi + f2[s_j[half][t + 128]]; e1 = e > 0.f ? e : ALPHA * e; }
  float m = fmaxf(e0, e1);
  #pragma unroll
  for (int o = 32; o; o >>= 1) m = fmaxf(m, __shfl_xor(m, o));
  if (lane == 0) s_red[half][hw] = m;
  __syncthreads();
  m = fmaxf(s_red[half][0], s_red[half][1]);
  float p0 = (t < nnz)       ? __expf(e0 - m) : 0.f;
  float p1 = (t + 128 < nnz) ? __expf(e1 - m) : 0.f;
  float s = p0 + p1;
  #pragma unroll
  for (int o = 32; o; o >>= 1) s += __shfl_xor(s, o);
  if (lane == 0) s_red[half][2 + hw] = s;
  __syncthreads();
  float rs = 1.0f / (s_red[half][2] + s_red[half][3]);
  if (t < nnz)       s_w[half][t]       = p0 * rs;
  if (t + 128 < nnz) s_w[half][t + 128] = p1 * rs;
  __syncthreads();
  if (t < 100) {
    float ax = 0.f, ay = 0.f;
    int jj = 0;
    for (; jj + 8 <= nnz; jj += 8) {
      #pragma unroll
      for (int q = 0; q < 8; q++) {
        int j = s_j[half][jj + q];
        float w = s_w[half][jj + q];
        u32 hv = *(const u32*)&hb[(size_t)j * FO + 2 * t];
        ax = fmaf(w, bf2f((u16)(hv & 0xffffu)), ax);
        ay = fmaf(w, bf2f((u16)(hv >> 16)), ay);
      }
    }
    for (; jj < nnz; jj++) {
      int j = s_j[half][jj];
      float w = s_w[half][jj];
      u32 hv = *(const u32*)&hb[(size_t)j * FO + 2 * t];
      ax = fmaf(w, bf2f((u16)(hv & 0xffffu)), ax);
      ay = fmaf(w, bf2f((u16)(hv >> 16)), ay);
    }
    s_hp[half][2 * t]     = ax > 0.f ? ax : expm1f(ax);
    s_hp[half][2 * t + 1] = ay > 0.f ? ay : expm1f(ay);
  }
  __syncthreads();
  if (t < 120) {
    int c = t % 20, dg = t / 20;
    float acc = 0.f;
    for (int d = dg; d < FO; d += 6)
      acc = fmaf(s_hp[half][d], W0[d * CO + c], acc);
    s_part[half][t] = acc;
  }
  __syncthreads();
  if (t < 20) {
    float a = s_part[half][t] + s_part[half][t + 20] + s_part[half][t + 40]
            + s_part[half][t + 60] + s_part[half][t + 80] + s_part[half][t + 100];
    g[(size_t)i * CO + t] = a;
  }
}

// ---------------- K3: out = support @ g  (sparse rep, LDS-staged) ------------
__launch_bounds__(256)
__global__ void k_out(const int* __restrict__ nnzg, const u16* __restrict__ idxg,
                      const float* __restrict__ valg, const float* __restrict__ g,
                      float* __restrict__ out){
  int tid = threadIdx.x, lane = tid & 63, wid = tid >> 6;
  int i = blockIdx.x * 4 + wid;
  __shared__ int s_j[4][CAP];
  __shared__ float s_w[4][CAP];
  int nnz = nnzg[i];
  for (int t = lane; t < nnz; t += 64) {
    s_j[wid][t] = idxg[(size_t)i * CAP + t];
    s_w[wid][t] = valg[(size_t)i * CAP + t];
  }
  __syncthreads();
  int c = lane % 20, grp = lane / 20;
  float acc = 0.f;
  if (grp < 3) {
    for (int jj = grp; jj < nnz; jj += 3)
      acc = fmaf(s_w[wid][jj], g[(size_t)s_j[wid][jj] * CO + c], acc);
  }
  float b1 = __shfl(acc, lane + 20);
  float b2 = __shfl(acc, lane + 40);
  if (lane < 20) out[(size_t)i * CO + lane] = acc + b1 + b2;
}

extern "C" void kernel_launch(void* const* d_in, const int* in_sizes, int n_in,
                              void* d_out, int out_size, void* d_ws, size_t ws_size,
                              hipStream_t stream) {
  (void)in_sizes; (void)n_in; (void)out_size; (void)ws_size;
  const float* x       = (const float*)d_in[0];
  const float* support = (const float*)d_in[1];
  const float* W       = (const float*)d_in[2];
  const float* a1      = (const float*)d_in[3];
  const float* a2      = (const float*)d_in[4];
  const float* W0      = (const float*)d_in[5];
  char* ws = (char*)d_ws;
  u16*   WbT  = (u16*)  (ws + 0);          // 208*512*2   = 212992
  float* f1   = (float*)(ws + 212992);     // 8192*4      = 32768
  float* f2   = (float*)(ws + 245760);     // 8192*4      = 32768
  u16*   hb   = (u16*)  (ws + 278528);     // 8192*200*2  = 3276800
  float* g    = (float*)(ws + 3555328);    // 8192*20*4   = 655360
  int*   nnzg = (int*)  (ws + 4210688);    // 8192*4      = 32768
  u16*   idxg = (u16*)  (ws + 4243456);    // 8192*256*2  = 4194304
  float* valg = (float*)(ws + 8437760);    // 8192*256*4  = 8388608
  float* outp = (float*)d_out;

  k_prep  <<<FP, 256, 0, stream>>>(W, WbT);
  k_main  <<<GEMM_BLOCKS + COMPACT_BLOCKS, 256, 0, stream>>>(support, x, WbT, a1, a2,
                                                             hb, f1, f2, nnzg, idxg, valg);
  k_gather<<<NN / 2, 256, 0, stream>>>(nnzg, idxg, f1, f2, hb, W0, g);
  k_out   <<<NN / 4, 256, 0, stream>>>(nnzg, idxg, valg, g, outp);
}

// Round 17
// 115.626 us; speedup vs baseline: 1.3150x; 1.0121x over previous
//
#include <hip/hip_runtime.h>

typedef unsigned short u16;
typedef unsigned int u32;
typedef unsigned long long u64;
typedef __attribute__((ext_vector_type(8))) short short8;
typedef __attribute__((ext_vector_type(4))) float f32x4;

#define NN 8192
#define FIN 512
#define FO 200
#define FP 208
#define CO 20
#define CAP 256
#define LCAP 12
#define ALPHA 0.2f
#define GEMM_BLOCKS 256
#define COMPACT_BLOCKS 2048

__device__ __forceinline__ u16 f2bf(float f){
  union { float f; unsigned u; } c; c.f = f;
  unsigned u = c.u;
  return (u16)((u + 0x7fffu + ((u >> 16) & 1u)) >> 16);
}
__device__ __forceinline__ float bf2f(u16 s){
  union { unsigned u; float f; } c; c.u = ((unsigned)s) << 16;
  return c.f;
}

struct SGemm {
  u16 As[32 * 32];
  u16 Bs[FP * 32];
  float a1s[FP], a2s[FP];
  float fpart[2][4][32];
};
struct SCompact {          // per-wave: 1536 + 3072 + 512 + 1024 = 6144 B
  u16   lidx[64 * LCAP];
  float lval[64 * LCAP];
  u16   cidx[CAP];
  float cval[CAP];
};

// ---- K0: WbT = bf16(W^T) padded to 208 cols (tiny) -------------------------
__launch_bounds__(256)
__global__ void k_prep(const float* __restrict__ W, u16* __restrict__ WbT){
  int b = blockIdx.x;
  for (int k = threadIdx.x; k < FIN; k += 256) {
    float v = (b < FO) ? W[(size_t)k * FO + b] : 0.f;
    WbT[(size_t)b * FIN + k] = f2bf(v);
  }
}

// ====== K1 fused: [0,256) gemm FIRST (overlaps) | [256,2304) compact ========
__launch_bounds__(256)
__global__ void k_main(const float* __restrict__ support, const float* __restrict__ x,
                       const u16* __restrict__ WbT, const float* __restrict__ a1,
                       const float* __restrict__ a2, u16* __restrict__ hb,
                       float* __restrict__ f1, float* __restrict__ f2,
                       int* __restrict__ nnzg, u16* __restrict__ idxg,
                       float* __restrict__ valg){
  __shared__ __align__(16) char smem[24576];
  int tid = threadIdx.x, lane = tid & 63, wid = tid >> 6;
  int bid = blockIdx.x;

  if (bid >= GEMM_BLOCKS) {
    // ==== compact role: per-lane LDS slab -> scan -> coalesced writeout ====
    int i = (bid - GEMM_BLOCKS) * 4 + wid;
    SCompact* sc = (SCompact*)(smem + wid * (int)sizeof(SCompact));
    const f32x4* row4 = (const f32x4*)(support + (size_t)i * NN);
    int lc = 0;
    int lbase = lane * LCAP;
    f32x4 bufA[8], bufB[8];
#define LOAD_GROUP(buf, g) { \
    _Pragma("unroll") \
    for (int k = 0; k < 8; k++) buf[k] = __builtin_nontemporal_load(&row4[(g) * 512 + k * 64 + lane]); }
#define PROC_GROUP(buf, g) { \
    _Pragma("unroll") \
    for (int k = 0; k < 8; k++) { \
      _Pragma("unroll") \
      for (int c = 0; c < 4; c++) { \
        float val = buf[k][c]; \
        if (val > 0.f) { \
          if (lc < LCAP) { \
            sc->lidx[lbase + lc] = (u16)((g) * 2048 + (k * 64 + lane) * 4 + c); \
            sc->lval[lbase + lc] = val; \
          } \
          lc++; \
        } \
      } } }
    LOAD_GROUP(bufA, 0)
    LOAD_GROUP(bufB, 1)
    PROC_GROUP(bufA, 0)
    LOAD_GROUP(bufA, 2)
    PROC_GROUP(bufB, 1)
    LOAD_GROUP(bufB, 3)
    PROC_GROUP(bufA, 2)
    PROC_GROUP(bufB, 3)
#undef LOAD_GROUP
#undef PROC_GROUP
    int cnt = min(lc, LCAP);
    int sc_ = cnt;
    #pragma unroll
    for (int o = 1; o < 64; o <<= 1) { int t2 = __shfl_up(sc_, o); if (lane >= o) sc_ += t2; }
    int pos = sc_ - cnt;
    int total = __shfl(sc_, 63);
    for (int c2 = 0; c2 < cnt; c2++) {
      int p = pos + c2;
      if (p < CAP) {
        sc->cidx[p] = sc->lidx[lbase + c2];
        sc->cval[p] = sc->lval[lbase + c2];
      }
    }
    // coalesced writeout: 2x u32 (idx) + 1x f32x4 (val) per lane
    u32* ig32 = (u32*)(idxg + (size_t)i * CAP);
    const u32* ci32 = (const u32*)sc->cidx;
    ig32[lane] = ci32[lane];
    ig32[lane + 64] = ci32[lane + 64];
    ((f32x4*)(valg + (size_t)i * CAP))[lane] = ((const f32x4*)sc->cval)[lane];
    if (lane == 0) nnzg[i] = min(total, CAP);
    return;
  }

  // ==== gemm role: A staged from f32 x directly, B from WbT ====
  SGemm* gs = (SGemm*)smem;
  int rb = bid * 32;
  if (tid < FP) {
    gs->a1s[tid] = (tid < FO) ? a1[tid] : 0.f;
    gs->a2s[tid] = (tid < FO) ? a2[tid] : 0.f;
  }
  f32x4 acc[7];
  #pragma unroll
  for (int n = 0; n < 7; n++) acc[n] = (f32x4){0.f, 0.f, 0.f, 0.f};
  for (int k0 = 0; k0 < FIN; k0 += 32) {
    __syncthreads();
    {
      int r = tid >> 3, kk = (tid & 7) * 4;
      const f32x4* xp = (const f32x4*)(x + (size_t)(rb + r) * FIN + k0 + kk);
      f32x4 xv = *xp;
      ushort4 hv;
      hv.x = f2bf(xv[0]); hv.y = f2bf(xv[1]); hv.z = f2bf(xv[2]); hv.w = f2bf(xv[3]);
      *(ushort4*)&gs->As[r * 32 + (((kk >> 3) ^ ((r >> 1) & 3)) * 8) + (kk & 7)] = hv;
    }
    for (int c = tid; c < FP * 4; c += 256) {
      int col = c >> 2, j = c & 3;
      uint4 bv = *(const uint4*)(WbT + (size_t)col * FIN + k0 + j * 8);
      *(uint4*)&gs->Bs[col * 32 + (j ^ ((col >> 1) & 3)) * 8] = bv;
    }
    __syncthreads();
    int jr = lane >> 4;
    #pragma unroll
    for (int n = 0; n < 7; n++) {
      int t = wid + 4 * n;
      if (t < 26) {
        int rt = t / 13, ct = t % 13;
        int lr = rt * 16 + (lane & 15);
        short8 af = *(const short8*)&gs->As[lr * 32 + (jr ^ ((lr >> 1) & 3)) * 8];
        int col = ct * 16 + (lane & 15);
        short8 bfv = *(const short8*)&gs->Bs[col * 32 + (jr ^ ((col >> 1) & 3)) * 8];
        acc[n] = __builtin_amdgcn_mfma_f32_16x16x32_bf16(af, bfv, acc[n], 0, 0, 0);
      }
    }
  }
  float f1a[2][4] = {{0.f,0.f,0.f,0.f},{0.f,0.f,0.f,0.f}};
  float f2a[2][4] = {{0.f,0.f,0.f,0.f},{0.f,0.f,0.f,0.f}};
  #pragma unroll
  for (int n = 0; n < 7; n++) {
    int t = wid + 4 * n;
    if (t < 26) {
      int rt = t / 13, ct = t % 13;
      int col = ct * 16 + (lane & 15);
      float av1 = gs->a1s[col], av2 = gs->a2s[col];
      int rbase = rb + rt * 16 + 4 * (lane >> 4);
      #pragma unroll
      for (int q = 0; q < 4; q++) {
        float hv = acc[n][q];
        if (col < FO) hb[(size_t)(rbase + q) * FO + col] = f2bf(hv);
        f1a[rt][q] = fmaf(hv, av1, f1a[rt][q]);
        f2a[rt][q] = fmaf(hv, av2, f2a[rt][q]);
      }
    }
  }
  #pragma unroll
  for (int rt = 0; rt < 2; rt++) {
    #pragma unroll
    for (int q = 0; q < 4; q++) {
      float v1 = f1a[rt][q], v2 = f2a[rt][q];
      #pragma unroll
      for (int o = 1; o < 16; o <<= 1) { v1 += __shfl_xor(v1, o); v2 += __shfl_xor(v2, o); }
      if ((lane & 15) == 0) {
        int row = rt * 16 + 4 * (lane >> 4) + q;
        gs->fpart[0][wid][row] = v1;
        gs->fpart[1][wid][row] = v2;
      }
    }
  }
  __syncthreads();
  if (tid < 32) {
    f1[rb + tid] = gs->fpart[0][0][tid] + gs->fpart[0][1][tid] + gs->fpart[0][2][tid] + gs->fpart[0][3][tid];
    f2[rb + tid] = gs->fpart[1][0][tid] + gs->fpart[1][1][tid] + gs->fpart[1][2][tid] + gs->fpart[1][3][tid];
  }
}

// ------- K2: softmax + h'=elu(att@h) + g = h'@W0  (2 rows/block) ------------
__launch_bounds__(256)
__global__ void k_gather(const int* __restrict__ nnzg, const u16* __restrict__ idxg,
                         const float* __restrict__ f1, const float* __restrict__ f2,
                         const u16* __restrict__ hb, const float* __restrict__ W0,
                         float* __restrict__ g){
  int tid = threadIdx.x;
  int half = tid >> 7, t = tid & 127;
  int lane = tid & 63, hw = (tid >> 6) & 1;
  int i = blockIdx.x * 2 + half;
  __shared__ int s_j[2][CAP];
  __shared__ float s_w[2][CAP];
  __shared__ float s_red[2][4];
  __shared__ float s_hp[2][FO];
  __shared__ float s_part[2][120];
  int nnz = nnzg[i];
  for (int u = t; u < nnz; u += 128) s_j[half][u] = idxg[(size_t)i * CAP + u];
  __syncthreads();
  float fi = f1[i];
  float e0 = -1e30f, e1 = -1e30f;
  if (t < nnz)       { float e = fi + f2[s_j[half][t]];       e0 = e > 0.f ? e : ALPHA * e; }
  if (t + 128 < nnz) { float e = fi + f2[s_j[half][t + 128]]; e1 = e > 0.f ? e : ALPHA * e; }
  float m = fmaxf(e0, e1);
  #pragma unroll
  for (int o = 32; o; o >>= 1) m = fmaxf(m, __shfl_xor(m, o));
  if (lane == 0) s_red[half][hw] = m;
  __syncthreads();
  m = fmaxf(s_red[half][0], s_red[half][1]);
  float p0 = (t < nnz)       ? __expf(e0 - m) : 0.f;
  float p1 = (t + 128 < nnz) ? __expf(e1 - m) : 0.f;
  float s = p0 + p1;
  #pragma unroll
  for (int o = 32; o; o >>= 1) s += __shfl_xor(s, o);
  if (lane == 0) s_red[half][2 + hw] = s;
  __syncthreads();
  float rs = 1.0f / (s_red[half][2] + s_red[half][3]);
  if (t < nnz)       s_w[half][t]       = p0 * rs;
  if (t + 128 < nnz) s_w[half][t + 128] = p1 * rs;
  __syncthreads();
  if (t < 100) {
    float ax = 0.f, ay = 0.f;
    int jj = 0;
    for (; jj + 8 <= nnz; jj += 8) {
      #pragma unroll
      for (int q = 0; q < 8; q++) {
        int j = s_j[half][jj + q];
        float w = s_w[half][jj + q];
        u32 hv = *(const u32*)&hb[(size_t)j * FO + 2 * t];
        ax = fmaf(w, bf2f((u16)(hv & 0xffffu)), ax);
        ay = fmaf(w, bf2f((u16)(hv >> 16)), ay);
      }
    }
    for (; jj < nnz; jj++) {
      int j = s_j[half][jj];
      float w = s_w[half][jj];
      u32 hv = *(const u32*)&hb[(size_t)j * FO + 2 * t];
      ax = fmaf(w, bf2f((u16)(hv & 0xffffu)), ax);
      ay = fmaf(w, bf2f((u16)(hv >> 16)), ay);
    }
    s_hp[half][2 * t]     = ax > 0.f ? ax : expm1f(ax);
    s_hp[half][2 * t + 1] = ay > 0.f ? ay : expm1f(ay);
  }
  __syncthreads();
  if (t < 120) {
    int c = t % 20, dg = t / 20;
    float acc = 0.f;
    for (int d = dg; d < FO; d += 6)
      acc = fmaf(s_hp[half][d], W0[d * CO + c], acc);
    s_part[half][t] = acc;
  }
  __syncthreads();
  if (t < 20) {
    float a = s_part[half][t] + s_part[half][t + 20] + s_part[half][t + 40]
            + s_part[half][t + 60] + s_part[half][t + 80] + s_part[half][t + 100];
    g[(size_t)i * CO + t] = a;
  }
}

// ---------------- K3: out = support @ g  (sparse rep, LDS-staged) ------------
__launch_bounds__(256)
__global__ void k_out(const int* __restrict__ nnzg, const u16* __restrict__ idxg,
                      const float* __restrict__ valg, const float* __restrict__ g,
                      float* __restrict__ out){
  int tid = threadIdx.x, lane = tid & 63, wid = tid >> 6;
  int i = blockIdx.x * 4 + wid;
  __shared__ int s_j[4][CAP];
  __shared__ float s_w[4][CAP];
  int nnz = nnzg[i];
  for (int t = lane; t < nnz; t += 64) {
    s_j[wid][t] = idxg[(size_t)i * CAP + t];
    s_w[wid][t] = valg[(size_t)i * CAP + t];
  }
  __syncthreads();
  int c = lane % 20, grp = lane / 20;
  float acc = 0.f;
  if (grp < 3) {
    for (int jj = grp; jj < nnz; jj += 3)
      acc = fmaf(s_w[wid][jj], g[(size_t)s_j[wid][jj] * CO + c], acc);
  }
  float b1 = __shfl(acc, lane + 20);
  float b2 = __shfl(acc, lane + 40);
  if (lane < 20) out[(size_t)i * CO + lane] = acc + b1 + b2;
}

extern "C" void kernel_launch(void* const* d_in, const int* in_sizes, int n_in,
                              void* d_out, int out_size, void* d_ws, size_t ws_size,
                              hipStream_t stream) {
  (void)in_sizes; (void)n_in; (void)out_size; (void)ws_size;
  const float* x       = (const float*)d_in[0];
  const float* support = (const float*)d_in[1];
  const float* W       = (const float*)d_in[2];
  const float* a1      = (const float*)d_in[3];
  const float* a2      = (const float*)d_in[4];
  const float* W0      = (const float*)d_in[5];
  char* ws = (char*)d_ws;
  u16*   WbT  = (u16*)  (ws + 0);          // 208*512*2   = 212992
  float* f1   = (float*)(ws + 212992);     // 8192*4      = 32768
  float* f2   = (float*)(ws + 245760);     // 8192*4      = 32768
  u16*   hb   = (u16*)  (ws + 278528);     // 8192*200*2  = 3276800
  float* g    = (float*)(ws + 3555328);    // 8192*20*4   = 655360
  int*   nnzg = (int*)  (ws + 4210688);    // 8192*4      = 32768
  u16*   idxg = (u16*)  (ws + 4243456);    // 8192*256*2  = 4194304
  float* valg = (float*)(ws + 8437760);    // 8192*256*4  = 8388608
  float* outp = (float*)d_out;

  k_prep  <<<FP, 256, 0, stream>>>(W, WbT);
  k_main  <<<GEMM_BLOCKS + COMPACT_BLOCKS, 256, 0, stream>>>(support, x, WbT, a1, a2,
                                                             hb, f1, f2, nnzg, idxg, valg);
  k_gather<<<NN / 2, 256, 0, stream>>>(nnzg, idxg, f1, f2, hb, W0, g);
  k_out   <<<NN / 4, 256, 0, stream>>>(nnzg, idxg, valg, g, outp);
}

// Round 18
// 111.532 us; speedup vs baseline: 1.3632x; 1.0367x over previous
//
#include <hip/hip_runtime.h>

typedef unsigned short u16;
typedef unsigned int u32;
typedef unsigned long long u64;
typedef __attribute__((ext_vector_type(8))) short short8;
typedef __attribute__((ext_vector_type(4))) float f32x4;

#define NN 8192
#define FIN 512
#define FO 200
#define FP 208
#define CO 20
#define CAP 256
#define ALPHA 0.2f
#define GEMM_BLOCKS 256
#define COMPACT_BLOCKS 2048

__device__ __forceinline__ u16 f2bf(float f){
  union { float f; unsigned u; } c; c.f = f;
  unsigned u = c.u;
  return (u16)((u + 0x7fffu + ((u >> 16) & 1u)) >> 16);
}
__device__ __forceinline__ float bf2f(u16 s){
  union { unsigned u; float f; } c; c.u = ((unsigned)s) << 16;
  return c.f;
}

// ---- K0: WbT = bf16(W^T) padded to 208 cols (tiny) -------------------------
__launch_bounds__(256)
__global__ void k_prep(const float* __restrict__ W, u16* __restrict__ WbT){
  int b = blockIdx.x;
  for (int k = threadIdx.x; k < FIN; k += 256) {
    float v = (b < FO) ? W[(size_t)k * FO + b] : 0.f;
    WbT[(size_t)b * FIN + k] = f2bf(v);
  }
}

// ====== K1 fused: [0,256) gemm FIRST (overlaps) | [256,2304) compact ========
__launch_bounds__(256)
__global__ void k_main(const float* __restrict__ support, const float* __restrict__ x,
                       const u16* __restrict__ WbT, const float* __restrict__ a1,
                       const float* __restrict__ a2, u16* __restrict__ hb,
                       float* __restrict__ f1, float* __restrict__ f2,
                       int* __restrict__ nnzg, u16* __restrict__ idxg,
                       float* __restrict__ valg){
  int tid = threadIdx.x, lane = tid & 63, wid = tid >> 6;
  int bid = blockIdx.x;

  if (bid >= GEMM_BLOCKS) {
    // ======== compact role: one row PER WAVE, no __syncthreads ========
    int i = (bid - GEMM_BLOCKS) * 4 + wid;
    const f32x4* row4 = (const f32x4*)(support + (size_t)i * NN);
    u16* ig = idxg + (size_t)i * CAP;
    float* vg = valg + (size_t)i * CAP;
    u64 lanemask = (1ull << lane) - 1ull;
    int base = 0;
    f32x4 bufA[8], bufB[8];
#define LOAD_GROUP(buf, g) { \
    _Pragma("unroll") \
    for (int k = 0; k < 8; k++) buf[k] = __builtin_nontemporal_load(&row4[(g) * 512 + k * 64 + lane]); }
#define PROC_GROUP(buf, g) { \
    _Pragma("unroll") \
    for (int k = 0; k < 8; k++) { \
      _Pragma("unroll") \
      for (int c = 0; c < 4; c++) { \
        float val = buf[k][c]; \
        bool p = val > 0.f; \
        u64 mk = __ballot(p); \
        if (p) { \
          int pos = base + __popcll(mk & lanemask); \
          if (pos < CAP) { \
            ig[pos] = (u16)((g) * 2048 + (k * 64 + lane) * 4 + c); \
            vg[pos] = val; \
          } \
        } \
        base += __popcll(mk); \
      } } }
    LOAD_GROUP(bufA, 0)
    LOAD_GROUP(bufB, 1)
    PROC_GROUP(bufA, 0)
    LOAD_GROUP(bufA, 2)
    PROC_GROUP(bufB, 1)
    LOAD_GROUP(bufB, 3)
    PROC_GROUP(bufA, 2)
    PROC_GROUP(bufB, 3)
#undef LOAD_GROUP
#undef PROC_GROUP
    if (lane == 0) nnzg[i] = min(base, CAP);
    return;
  }

  // ======== gemm role: A staged from f32 x directly, B from WbT (fast) ======
  __shared__ __align__(16) u16 As[32 * 32];
  __shared__ __align__(16) u16 Bs[FP * 32];
  __shared__ float a1s[FP], a2s[FP];
  __shared__ float fpart[2][4][32];
  int rb = bid * 32;
  if (tid < FP) {
    a1s[tid] = (tid < FO) ? a1[tid] : 0.f;
    a2s[tid] = (tid < FO) ? a2[tid] : 0.f;
  }
  f32x4 acc[7];
  #pragma unroll
  for (int n = 0; n < 7; n++) acc[n] = (f32x4){0.f, 0.f, 0.f, 0.f};
  for (int k0 = 0; k0 < FIN; k0 += 32) {
    __syncthreads();
    {
      int r = tid >> 3, kk = (tid & 7) * 4;
      const f32x4* xp = (const f32x4*)(x + (size_t)(rb + r) * FIN + k0 + kk);
      f32x4 xv = *xp;
      ushort4 hv;
      hv.x = f2bf(xv[0]); hv.y = f2bf(xv[1]); hv.z = f2bf(xv[2]); hv.w = f2bf(xv[3]);
      *(ushort4*)&As[r * 32 + (((kk >> 3) ^ ((r >> 1) & 3)) * 8) + (kk & 7)] = hv;
    }
    for (int c = tid; c < FP * 4; c += 256) {
      int col = c >> 2, j = c & 3;
      uint4 bv = *(const uint4*)(WbT + (size_t)col * FIN + k0 + j * 8);
      *(uint4*)&Bs[col * 32 + (j ^ ((col >> 1) & 3)) * 8] = bv;
    }
    __syncthreads();
    int jr = lane >> 4;
    #pragma unroll
    for (int n = 0; n < 7; n++) {
      int t = wid + 4 * n;
      if (t < 26) {
        int rt = t / 13, ct = t % 13;
        int lr = rt * 16 + (lane & 15);
        short8 af = *(const short8*)&As[lr * 32 + (jr ^ ((lr >> 1) & 3)) * 8];
        int col = ct * 16 + (lane & 15);
        short8 bfv = *(const short8*)&Bs[col * 32 + (jr ^ ((col >> 1) & 3)) * 8];
        acc[n] = __builtin_amdgcn_mfma_f32_16x16x32_bf16(af, bfv, acc[n], 0, 0, 0);
      }
    }
  }
  float f1a[2][4] = {{0.f,0.f,0.f,0.f},{0.f,0.f,0.f,0.f}};
  float f2a[2][4] = {{0.f,0.f,0.f,0.f},{0.f,0.f,0.f,0.f}};
  #pragma unroll
  for (int n = 0; n < 7; n++) {
    int t = wid + 4 * n;
    if (t < 26) {
      int rt = t / 13, ct = t % 13;
      int col = ct * 16 + (lane & 15);
      float av1 = a1s[col], av2 = a2s[col];
      int rbase = rb + rt * 16 + 4 * (lane >> 4);
      #pragma unroll
      for (int q = 0; q < 4; q++) {
        float hv = acc[n][q];
        if (col < FO) hb[(size_t)(rbase + q) * FO + col] = f2bf(hv);
        f1a[rt][q] = fmaf(hv, av1, f1a[rt][q]);
        f2a[rt][q] = fmaf(hv, av2, f2a[rt][q]);
      }
    }
  }
  #pragma unroll
  for (int rt = 0; rt < 2; rt++) {
    #pragma unroll
    for (int q = 0; q < 4; q++) {
      float v1 = f1a[rt][q], v2 = f2a[rt][q];
      #pragma unroll
      for (int o = 1; o < 16; o <<= 1) { v1 += __shfl_xor(v1, o); v2 += __shfl_xor(v2, o); }
      if ((lane & 15) == 0) {
        int row = rt * 16 + 4 * (lane >> 4) + q;
        fpart[0][wid][row] = v1;
        fpart[1][wid][row] = v2;
      }
    }
  }
  __syncthreads();
  if (tid < 32) {
    f1[rb + tid] = fpart[0][0][tid] + fpart[0][1][tid] + fpart[0][2][tid] + fpart[0][3][tid];
    f2[rb + tid] = fpart[1][0][tid] + fpart[1][1][tid] + fpart[1][2][tid] + fpart[1][3][tid];
  }
}

// ------- K2: softmax + h'=elu(att@h) + g = h'@W0  (2 rows/block) ------------
__launch_bounds__(256)
__global__ void k_gather(const int* __restrict__ nnzg, const u16* __restrict__ idxg,
                         const float* __restrict__ f1, const float* __restrict__ f2,
                         const u16* __restrict__ hb, const float* __restrict__ W0,
                         float* __restrict__ g){
  int tid = threadIdx.x;
  int half = tid >> 7, t = tid & 127;
  int lane = tid & 63, hw = (tid >> 6) & 1;
  int i = blockIdx.x * 2 + half;
  __shared__ int s_j[2][CAP];
  __shared__ float s_w[2][CAP];
  __shared__ float s_red[2][4];
  __shared__ float s_hp[2][FO];
  __shared__ float s_part[2][120];
  int nnz = nnzg[i];
  for (int u = t; u < nnz; u += 128) s_j[half][u] = idxg[(size_t)i * CAP + u];
  __syncthreads();
  float fi = f1[i];
  float e0 = -1e30f, e1 = -1e30f;
  if (t < nnz)       { float e = fi + f2[s_j[half][t]];       e0 = e > 0.f ? e : ALPHA * e; }
  if (t + 128 < nnz) { float e = fi + f2[s_j[half][t + 128]]; e1 = e > 0.f ? e : ALPHA * e; }
  float m = fmaxf(e0, e1);
  #pragma unroll
  for (int o = 32; o; o >>= 1) m = fmaxf(m, __shfl_xor(m, o));
  if (lane == 0) s_red[half][hw] = m;
  __syncthreads();
  m = fmaxf(s_red[half][0], s_red[half][1]);
  float p0 = (t < nnz)       ? __expf(e0 - m) : 0.f;
  float p1 = (t + 128 < nnz) ? __expf(e1 - m) : 0.f;
  float s = p0 + p1;
  #pragma unroll
  for (int o = 32; o; o >>= 1) s += __shfl_xor(s, o);
  if (lane == 0) s_red[half][2 + hw] = s;
  __syncthreads();
  float rs = 1.0f / (s_red[half][2] + s_red[half][3]);
  if (t < nnz)       s_w[half][t]       = p0 * rs;
  if (t + 128 < nnz) s_w[half][t + 128] = p1 * rs;
  __syncthreads();
  if (t < 100) {
    float ax = 0.f, ay = 0.f;
    int jj = 0;
    for (; jj + 8 <= nnz; jj += 8) {
      #pragma unroll
      for (int q = 0; q < 8; q++) {
        int j = s_j[half][jj + q];
        float w = s_w[half][jj + q];
        u32 hv = *(const u32*)&hb[(size_t)j * FO + 2 * t];
        ax = fmaf(w, bf2f((u16)(hv & 0xffffu)), ax);
        ay = fmaf(w, bf2f((u16)(hv >> 16)), ay);
      }
    }
    for (; jj < nnz; jj++) {
      int j = s_j[half][jj];
      float w = s_w[half][jj];
      u32 hv = *(const u32*)&hb[(size_t)j * FO + 2 * t];
      ax = fmaf(w, bf2f((u16)(hv & 0xffffu)), ax);
      ay = fmaf(w, bf2f((u16)(hv >> 16)), ay);
    }
    s_hp[half][2 * t]     = ax > 0.f ? ax : expm1f(ax);
    s_hp[half][2 * t + 1] = ay > 0.f ? ay : expm1f(ay);
  }
  __syncthreads();
  if (t < 120) {
    int c = t % 20, dg = t / 20;
    float acc = 0.f;
    for (int d = dg; d < FO; d += 6)
      acc = fmaf(s_hp[half][d], W0[d * CO + c], acc);
    s_part[half][t] = acc;
  }
  __syncthreads();
  if (t < 20) {
    float a = s_part[half][t] + s_part[half][t + 20] + s_part[half][t + 40]
            + s_part[half][t + 60] + s_part[half][t + 80] + s_part[half][t + 100];
    g[(size_t)i * CO + t] = a;
  }
}

// ---------------- K3: out = support @ g  (sparse rep, LDS-staged) ------------
__launch_bounds__(256)
__global__ void k_out(const int* __restrict__ nnzg, const u16* __restrict__ idxg,
                      const float* __restrict__ valg, const float* __restrict__ g,
                      float* __restrict__ out){
  int tid = threadIdx.x, lane = tid & 63, wid = tid >> 6;
  int i = blockIdx.x * 4 + wid;
  __shared__ int s_j[4][CAP];
  __shared__ float s_w[4][CAP];
  int nnz = nnzg[i];
  for (int t = lane; t < nnz; t += 64) {
    s_j[wid][t] = idxg[(size_t)i * CAP + t];
    s_w[wid][t] = valg[(size_t)i * CAP + t];
  }
  __syncthreads();
  int c = lane % 20, grp = lane / 20;
  float acc = 0.f;
  if (grp < 3) {
    for (int jj = grp; jj < nnz; jj += 3)
      acc = fmaf(s_w[wid][jj], g[(size_t)s_j[wid][jj] * CO + c], acc);
  }
  float b1 = __shfl(acc, lane + 20);
  float b2 = __shfl(acc, lane + 40);
  if (lane < 20) out[(size_t)i * CO + lane] = acc + b1 + b2;
}

extern "C" void kernel_launch(void* const* d_in, const int* in_sizes, int n_in,
                              void* d_out, int out_size, void* d_ws, size_t ws_size,
                              hipStream_t stream) {
  (void)in_sizes; (void)n_in; (void)out_size; (void)ws_size;
  const float* x       = (const float*)d_in[0];
  const float* support = (const float*)d_in[1];
  const float* W       = (const float*)d_in[2];
  const float* a1      = (const float*)d_in[3];
  const float* a2      = (const float*)d_in[4];
  const float* W0      = (const float*)d_in[5];
  char* ws = (char*)d_ws;
  u16*   WbT  = (u16*)  (ws + 0);          // 208*512*2   = 212992
  float* f1   = (float*)(ws + 212992);     // 8192*4      = 32768
  float* f2   = (float*)(ws + 245760);     // 8192*4      = 32768
  u16*   hb   = (u16*)  (ws + 278528);     // 8192*200*2  = 3276800
  float* g    = (float*)(ws + 3555328);    // 8192*20*4   = 655360
  int*   nnzg = (int*)  (ws + 4210688);    // 8192*4      = 32768
  u16*   idxg = (u16*)  (ws + 4243456);    // 8192*256*2  = 4194304
  float* valg = (float*)(ws + 8437760);    // 8192*256*4  = 8388608
  float* outp = (float*)d_out;

  k_prep  <<<FP, 256, 0, stream>>>(W, WbT);
  k_main  <<<GEMM_BLOCKS + COMPACT_BLOCKS, 256, 0, stream>>>(support, x, WbT, a1, a2,
                                                             hb, f1, f2, nnzg, idxg, valg);
  k_gather<<<NN / 2, 256, 0, stream>>>(nnzg, idxg, f1, f2, hb, W0, g);
  k_out   <<<NN / 4, 256, 0, stream>>>(nnzg, idxg, valg, g, outp);
}